// Round 1
// baseline (5872.257 us; speedup 1.0000x reference)
//
#include <hip/hip_runtime.h>
#include <hip/hip_bf16.h>

#define D 128
#define PH 128

// ---------------- edge counting sort + degree ----------------

__global__ void k_count(const int* __restrict__ etype, const int* __restrict__ dst,
                        int E, int N, int* __restrict__ deg, int* __restrict__ counts) {
    int e = blockIdx.x * blockDim.x + threadIdx.x;
    if (e < E) {
        int r = etype[e];
        atomicAdd(&deg[r * N + dst[e]], 1);
        atomicAdd(&counts[r], 1);
    }
}

__global__ void k_offsets(const int* __restrict__ counts, int* __restrict__ offsets,
                          int* __restrict__ cursors, int R) {
    if (threadIdx.x == 0 && blockIdx.x == 0) {
        int acc = 0;
        for (int r = 0; r < R; ++r) {
            offsets[r] = acc;
            cursors[r] = acc;
            acc += counts[r];
        }
        offsets[R] = acc;
    }
}

__global__ void k_scatter(const int* __restrict__ etype, int E,
                          int* __restrict__ cursors, int* __restrict__ perm) {
    int e = blockIdx.x * blockDim.x + threadIdx.x;
    if (e < E) {
        int r = etype[e];
        int pos = atomicAdd(&cursors[r], 1);
        perm[pos] = e;
    }
}

// ---------------- self-loop + bias: out = bias + act(x) @ sl ----------------

template<bool ACT>
__global__ void k_self(const float* __restrict__ x, const float* __restrict__ sl,
                       const float* __restrict__ bias, float* __restrict__ out, int N) {
    __shared__ float xs[16][D];
    int n0 = blockIdx.x * 16;
    int j = threadIdx.x;   // 0..127

    #pragma unroll
    for (int m = 0; m < 16; ++m) {
        int n = n0 + m;
        float v = (n < N) ? x[(size_t)n * D + j] : 0.0f;
        if (ACT) v = fmaxf(v, 0.0f);
        xs[m][j] = v;
    }
    __syncthreads();

    float b = bias[j];
    float acc[16];
    #pragma unroll
    for (int m = 0; m < 16; ++m) acc[m] = b;

    for (int k = 0; k < D; ++k) {
        float w = sl[(size_t)k * D + j];
        #pragma unroll
        for (int m = 0; m < 16; ++m) acc[m] = fmaf(xs[m][k], w, acc[m]);
    }

    #pragma unroll
    for (int m = 0; m < 16; ++m) {
        int n = n0 + m;
        if (n < N) out[(size_t)n * D + j] = acc[m];
    }
}

// ---------------- edge messages: out[dst] += (act(x[src]) @ rw[r]) / deg ----------------

template<bool ACT>
__global__ void k_edge(const float* __restrict__ x, const float* __restrict__ rw,
                       const int* __restrict__ srcA, const int* __restrict__ dstA,
                       const int* __restrict__ etype, const int* __restrict__ perm,
                       const int* __restrict__ deg, int E, int N,
                       float* __restrict__ out) {
    const int EB = 16;
    __shared__ float xs[EB][D];
    __shared__ int   ssrc[EB];
    __shared__ int   sdst[EB];
    __shared__ int   srel[EB];
    __shared__ float sscale[EB];

    int e0 = blockIdx.x * EB;
    int j = threadIdx.x;   // 0..127

    if (j < EB) {
        int ei = e0 + j;
        if (ei < E) {
            int e = perm[ei];
            int r = etype[e];
            int d = dstA[e];
            int s = srcA[e];
            srel[j] = r;
            sdst[j] = d;
            ssrc[j] = s;
            int dg = deg[r * N + d];
            if (dg < 1) dg = 1;
            sscale[j] = 1.0f / (float)dg;
        } else {
            srel[j] = -1; sdst[j] = 0; ssrc[j] = 0; sscale[j] = 0.0f;
        }
    }
    __syncthreads();

    #pragma unroll
    for (int m = 0; m < EB; ++m) {
        float v = (srel[m] >= 0) ? x[(size_t)ssrc[m] * D + j] : 0.0f;
        if (ACT) v = fmaxf(v, 0.0f);
        xs[m][j] = v;
    }
    __syncthreads();

    // perm is sorted by relation, so a block is almost always single-relation.
    if (srel[0] == srel[EB - 1] && srel[0] >= 0) {
        const float* __restrict__ W = rw + (size_t)srel[0] * D * D;
        float acc[EB];
        #pragma unroll
        for (int m = 0; m < EB; ++m) acc[m] = 0.0f;
        for (int k = 0; k < D; ++k) {
            float w = W[(size_t)k * D + j];
            #pragma unroll
            for (int m = 0; m < EB; ++m) acc[m] = fmaf(xs[m][k], w, acc[m]);
        }
        #pragma unroll
        for (int m = 0; m < EB; ++m) {
            atomicAdd(&out[(size_t)sdst[m] * D + j], acc[m] * sscale[m]);
        }
    } else {
        // boundary / tail block: per-edge path
        for (int m = 0; m < EB; ++m) {
            int r = srel[m];
            if (r < 0) continue;
            const float* __restrict__ W = rw + (size_t)r * D * D;
            float a = 0.0f;
            for (int k = 0; k < D; ++k) a = fmaf(xs[m][k], W[(size_t)k * D + j], a);
            atomicAdd(&out[(size_t)sdst[m] * D + j], a * sscale[m]);
        }
    }
}

// ---------------- pair scoring ----------------

__global__ void k_score(const float* __restrict__ x2, const int* __restrict__ drug,
                        const int* __restrict__ dis, const float* __restrict__ pw1,
                        const float* __restrict__ pb1, const float* __restrict__ pw2,
                        const float* __restrict__ pb2, float* __restrict__ out, int P) {
    const int PB = 16;
    __shared__ float fs[PB][3 * D];     // 24 KiB
    __shared__ float red[PB][PH];       // 8 KiB

    int p0 = blockIdx.x * PB;
    int j = threadIdx.x;   // 0..127

    #pragma unroll
    for (int m = 0; m < PB; ++m) {
        int p = p0 + m;
        float a = 0.0f, b = 0.0f;
        if (p < P) {
            a = x2[(size_t)drug[p] * D + j];
            b = x2[(size_t)dis[p]  * D + j];
        }
        fs[m][j]         = a;
        fs[m][D + j]     = b;
        fs[m][2 * D + j] = a * b;
    }
    __syncthreads();

    float bb = pb1[j];
    float acc[PB];
    #pragma unroll
    for (int m = 0; m < PB; ++m) acc[m] = bb;

    for (int k = 0; k < 3 * D; ++k) {
        float w = pw1[(size_t)k * PH + j];
        #pragma unroll
        for (int m = 0; m < PB; ++m) acc[m] = fmaf(fs[m][k], w, acc[m]);
    }

    float w2 = pw2[j];
    #pragma unroll
    for (int m = 0; m < PB; ++m) red[m][j] = fmaxf(acc[m], 0.0f) * w2;
    __syncthreads();

    for (int s = 64; s > 0; s >>= 1) {
        if (j < s) {
            #pragma unroll
            for (int m = 0; m < PB; ++m) red[m][j] += red[m][j + s];
        }
        __syncthreads();
    }
    if (j < PB) {
        int p = p0 + j;
        if (p < P) out[p] = red[j][0] + pb2[0];
    }
}

// ---------------- launch ----------------

extern "C" void kernel_launch(void* const* d_in, const int* in_sizes, int n_in,
                              void* d_out, int out_size, void* d_ws, size_t ws_size,
                              hipStream_t stream) {
    const int*   edge_index = (const int*)d_in[0];
    const int*   edge_type  = (const int*)d_in[1];
    const int*   drug       = (const int*)d_in[2];
    const int*   dis        = (const int*)d_in[3];
    const float* emb        = (const float*)d_in[4];
    const float* rw1        = (const float*)d_in[5];
    const float* sl1        = (const float*)d_in[6];
    const float* b1         = (const float*)d_in[7];
    const float* rw2        = (const float*)d_in[8];
    const float* sl2        = (const float*)d_in[9];
    const float* b2         = (const float*)d_in[10];
    const float* pw1        = (const float*)d_in[11];
    const float* pb1        = (const float*)d_in[12];
    const float* pw2        = (const float*)d_in[13];
    const float* pb2        = (const float*)d_in[14];

    const int E = in_sizes[1];
    const int P = in_sizes[2];
    const int N = in_sizes[4] / D;
    const int R = in_sizes[5] / (D * D);

    const int* srcA = edge_index;
    const int* dstA = edge_index + E;

    char* ws = (char*)d_ws;
    float* x1   = (float*)ws;  ws += (size_t)N * D * 4;
    float* x2   = (float*)ws;  ws += (size_t)N * D * 4;
    int*   deg  = (int*)ws;    ws += (size_t)R * N * 4;
    int*   perm = (int*)ws;    ws += (size_t)E * 4;
    int*   counts  = (int*)ws; ws += 64;
    int*   offsets = (int*)ws; ws += 64;
    int*   cursors = (int*)ws; ws += 64;

    hipMemsetAsync(deg, 0, (size_t)R * N * 4, stream);
    hipMemsetAsync(counts, 0, 192, stream);

    k_count  <<<(E + 255) / 256, 256, 0, stream>>>(edge_type, dstA, E, N, deg, counts);
    k_offsets<<<1, 1, 0, stream>>>(counts, offsets, cursors, R);
    k_scatter<<<(E + 255) / 256, 256, 0, stream>>>(edge_type, E, cursors, perm);

    // layer 1
    k_self<false><<<(N + 15) / 16, 128, 0, stream>>>(emb, sl1, b1, x1, N);
    k_edge<false><<<(E + 15) / 16, 128, 0, stream>>>(emb, rw1, srcA, dstA, edge_type,
                                                     perm, deg, E, N, x1);
    // layer 2 (relu fused into reads)
    k_self<true><<<(N + 15) / 16, 128, 0, stream>>>(x1, sl2, b2, x2, N);
    k_edge<true><<<(E + 15) / 16, 128, 0, stream>>>(x1, rw2, srcA, dstA, edge_type,
                                                    perm, deg, E, N, x2);
    // scoring
    k_score<<<(P + 15) / 16, 128, 0, stream>>>(x2, drug, dis, pw1, pb1, pw2, pb2,
                                               (float*)d_out, P);
}

// Round 2
// 1320.997 us; speedup vs baseline: 4.4453x; 4.4453x over previous
//
#include <hip/hip_runtime.h>
#include <hip/hip_bf16.h>

#define D 128
#define PH 128
#define RMAX 16

// ---------------- edge counting sort + degree (LDS-aggregated atomics) ----------------

__global__ void k_count(const int* __restrict__ etype, const int* __restrict__ dst,
                        int E, int N, int R, int* __restrict__ deg, int* __restrict__ counts) {
    __shared__ int lh[RMAX];
    if (threadIdx.x < RMAX) lh[threadIdx.x] = 0;
    __syncthreads();
    int e = blockIdx.x * blockDim.x + threadIdx.x;
    if (e < E) {
        int r = etype[e];
        atomicAdd(&deg[r * N + dst[e]], 1);
        atomicAdd(&lh[r], 1);
    }
    __syncthreads();
    if (threadIdx.x < R && lh[threadIdx.x])
        atomicAdd(&counts[threadIdx.x], lh[threadIdx.x]);
}

__global__ void k_offsets(const int* __restrict__ counts, int* __restrict__ offsets,
                          int* __restrict__ cursors, int R) {
    if (threadIdx.x == 0 && blockIdx.x == 0) {
        int acc = 0;
        for (int r = 0; r < R; ++r) {
            offsets[r] = acc;
            cursors[r] = acc;
            acc += counts[r];
        }
        offsets[R] = acc;
    }
}

__global__ void k_scatter(const int* __restrict__ etype, int E, int R,
                          int* __restrict__ cursors, int* __restrict__ perm) {
    __shared__ int lh[RMAX];
    __shared__ int lbase[RMAX];
    __shared__ int lcur[RMAX];
    if (threadIdx.x < RMAX) lh[threadIdx.x] = 0;
    __syncthreads();

    int e = blockIdx.x * blockDim.x + threadIdx.x;
    int r = -1;
    if (e < E) {
        r = etype[e];
        atomicAdd(&lh[r], 1);
    }
    __syncthreads();
    if (threadIdx.x < R) {
        lbase[threadIdx.x] = lh[threadIdx.x] ? atomicAdd(&cursors[threadIdx.x], lh[threadIdx.x]) : 0;
        lcur[threadIdx.x] = 0;
    }
    __syncthreads();
    if (e < E) {
        int pos = lbase[r] + atomicAdd(&lcur[r], 1);
        perm[pos] = e;
    }
}

// ---------------- self-loop + bias: out = bias + act(x) @ sl ----------------

template<bool ACT>
__global__ void k_self(const float* __restrict__ x, const float* __restrict__ sl,
                       const float* __restrict__ bias, float* __restrict__ out, int N) {
    __shared__ float xs[16][D];
    int n0 = blockIdx.x * 16;
    int j = threadIdx.x;   // 0..127

    #pragma unroll
    for (int m = 0; m < 16; ++m) {
        int n = n0 + m;
        float v = (n < N) ? x[(size_t)n * D + j] : 0.0f;
        if (ACT) v = fmaxf(v, 0.0f);
        xs[m][j] = v;
    }
    __syncthreads();

    float b = bias[j];
    float acc[16];
    #pragma unroll
    for (int m = 0; m < 16; ++m) acc[m] = b;

    for (int k = 0; k < D; ++k) {
        float w = sl[(size_t)k * D + j];
        #pragma unroll
        for (int m = 0; m < 16; ++m) acc[m] = fmaf(xs[m][k], w, acc[m]);
    }

    #pragma unroll
    for (int m = 0; m < 16; ++m) {
        int n = n0 + m;
        if (n < N) out[(size_t)n * D + j] = acc[m];
    }
}

// ---------------- edge messages: out[dst] += (act(x[src]) @ rw[r]) / deg ----------------

template<bool ACT>
__global__ void k_edge(const float* __restrict__ x, const float* __restrict__ rw,
                       const int* __restrict__ srcA, const int* __restrict__ dstA,
                       const int* __restrict__ etype, const int* __restrict__ perm,
                       const int* __restrict__ deg, int E, int N,
                       float* __restrict__ out) {
    const int EB = 16;
    __shared__ float xs[EB][D];
    __shared__ int   ssrc[EB];
    __shared__ int   sdst[EB];
    __shared__ int   srel[EB];
    __shared__ float sscale[EB];

    int e0 = blockIdx.x * EB;
    int j = threadIdx.x;   // 0..127

    if (j < EB) {
        int ei = e0 + j;
        if (ei < E) {
            int e = perm[ei];
            int r = etype[e];
            int d = dstA[e];
            int s = srcA[e];
            srel[j] = r;
            sdst[j] = d;
            ssrc[j] = s;
            int dg = deg[r * N + d];
            if (dg < 1) dg = 1;
            sscale[j] = 1.0f / (float)dg;
        } else {
            srel[j] = -1; sdst[j] = 0; ssrc[j] = 0; sscale[j] = 0.0f;
        }
    }
    __syncthreads();

    #pragma unroll
    for (int m = 0; m < EB; ++m) {
        float v = (srel[m] >= 0) ? x[(size_t)ssrc[m] * D + j] : 0.0f;
        if (ACT) v = fmaxf(v, 0.0f);
        xs[m][j] = v;
    }
    __syncthreads();

    // perm is sorted by relation, so a block is almost always single-relation.
    if (srel[0] == srel[EB - 1] && srel[0] >= 0) {
        const float* __restrict__ W = rw + (size_t)srel[0] * D * D;
        float acc[EB];
        #pragma unroll
        for (int m = 0; m < EB; ++m) acc[m] = 0.0f;
        for (int k = 0; k < D; ++k) {
            float w = W[(size_t)k * D + j];
            #pragma unroll
            for (int m = 0; m < EB; ++m) acc[m] = fmaf(xs[m][k], w, acc[m]);
        }
        #pragma unroll
        for (int m = 0; m < EB; ++m) {
            atomicAdd(&out[(size_t)sdst[m] * D + j], acc[m] * sscale[m]);
        }
    } else {
        // boundary / tail block: per-edge path
        for (int m = 0; m < EB; ++m) {
            int r = srel[m];
            if (r < 0) continue;
            const float* __restrict__ W = rw + (size_t)r * D * D;
            float a = 0.0f;
            for (int k = 0; k < D; ++k) a = fmaf(xs[m][k], W[(size_t)k * D + j], a);
            atomicAdd(&out[(size_t)sdst[m] * D + j], a * sscale[m]);
        }
    }
}

// ---------------- pair scoring ----------------

__global__ void k_score(const float* __restrict__ x2, const int* __restrict__ drug,
                        const int* __restrict__ dis, const float* __restrict__ pw1,
                        const float* __restrict__ pb1, const float* __restrict__ pw2,
                        const float* __restrict__ pb2, float* __restrict__ out, int P) {
    const int PB = 16;
    __shared__ float fs[PB][3 * D];     // 24 KiB
    __shared__ float red[PB][PH];       // 8 KiB

    int p0 = blockIdx.x * PB;
    int j = threadIdx.x;   // 0..127

    #pragma unroll
    for (int m = 0; m < PB; ++m) {
        int p = p0 + m;
        float a = 0.0f, b = 0.0f;
        if (p < P) {
            a = x2[(size_t)drug[p] * D + j];
            b = x2[(size_t)dis[p]  * D + j];
        }
        fs[m][j]         = a;
        fs[m][D + j]     = b;
        fs[m][2 * D + j] = a * b;
    }
    __syncthreads();

    float bb = pb1[j];
    float acc[PB];
    #pragma unroll
    for (int m = 0; m < PB; ++m) acc[m] = bb;

    for (int k = 0; k < 3 * D; ++k) {
        float w = pw1[(size_t)k * PH + j];
        #pragma unroll
        for (int m = 0; m < PB; ++m) acc[m] = fmaf(fs[m][k], w, acc[m]);
    }

    float w2 = pw2[j];
    #pragma unroll
    for (int m = 0; m < PB; ++m) red[m][j] = fmaxf(acc[m], 0.0f) * w2;
    __syncthreads();

    for (int s = 64; s > 0; s >>= 1) {
        if (j < s) {
            #pragma unroll
            for (int m = 0; m < PB; ++m) red[m][j] += red[m][j + s];
        }
        __syncthreads();
    }
    if (j < PB) {
        int p = p0 + j;
        if (p < P) out[p] = red[j][0] + pb2[0];
    }
}

// ---------------- launch ----------------

extern "C" void kernel_launch(void* const* d_in, const int* in_sizes, int n_in,
                              void* d_out, int out_size, void* d_ws, size_t ws_size,
                              hipStream_t stream) {
    const int*   edge_index = (const int*)d_in[0];
    const int*   edge_type  = (const int*)d_in[1];
    const int*   drug       = (const int*)d_in[2];
    const int*   dis        = (const int*)d_in[3];
    const float* emb        = (const float*)d_in[4];
    const float* rw1        = (const float*)d_in[5];
    const float* sl1        = (const float*)d_in[6];
    const float* b1         = (const float*)d_in[7];
    const float* rw2        = (const float*)d_in[8];
    const float* sl2        = (const float*)d_in[9];
    const float* b2         = (const float*)d_in[10];
    const float* pw1        = (const float*)d_in[11];
    const float* pb1        = (const float*)d_in[12];
    const float* pw2        = (const float*)d_in[13];
    const float* pb2        = (const float*)d_in[14];

    const int E = in_sizes[1];
    const int P = in_sizes[2];
    const int N = in_sizes[4] / D;
    const int R = in_sizes[5] / (D * D);

    const int* srcA = edge_index;
    const int* dstA = edge_index + E;

    char* ws = (char*)d_ws;
    float* x1   = (float*)ws;  ws += (size_t)N * D * 4;
    float* x2   = (float*)ws;  ws += (size_t)N * D * 4;
    int*   deg  = (int*)ws;    ws += (size_t)R * N * 4;
    int*   perm = (int*)ws;    ws += (size_t)E * 4;
    int*   counts  = (int*)ws; ws += 64 * 4;
    int*   offsets = (int*)ws; ws += 64 * 4;
    int*   cursors = (int*)ws; ws += 64 * 4;

    hipMemsetAsync(deg, 0, (size_t)R * N * 4, stream);
    hipMemsetAsync(counts, 0, 64 * 4, stream);

    k_count  <<<(E + 255) / 256, 256, 0, stream>>>(edge_type, dstA, E, N, R, deg, counts);
    k_offsets<<<1, 1, 0, stream>>>(counts, offsets, cursors, R);
    k_scatter<<<(E + 255) / 256, 256, 0, stream>>>(edge_type, E, R, cursors, perm);

    // layer 1
    k_self<false><<<(N + 15) / 16, 128, 0, stream>>>(emb, sl1, b1, x1, N);
    k_edge<false><<<(E + 15) / 16, 128, 0, stream>>>(emb, rw1, srcA, dstA, edge_type,
                                                     perm, deg, E, N, x1);
    // layer 2 (relu fused into reads)
    k_self<true><<<(N + 15) / 16, 128, 0, stream>>>(x1, sl2, b2, x2, N);
    k_edge<true><<<(E + 15) / 16, 128, 0, stream>>>(x1, rw2, srcA, dstA, edge_type,
                                                    perm, deg, E, N, x2);
    // scoring
    k_score<<<(P + 15) / 16, 128, 0, stream>>>(x2, drug, dis, pw1, pb1, pw2, pb2,
                                               (float*)d_out, P);
}

// Round 3
// 732.663 us; speedup vs baseline: 8.0149x; 1.8030x over previous
//
#include <hip/hip_runtime.h>

#define D 128
#define RMAX 16

typedef short s16x8 __attribute__((ext_vector_type(8)));
typedef float f32x4 __attribute__((ext_vector_type(4)));

__device__ inline unsigned short f2b(float f) {
    unsigned u = __builtin_bit_cast(unsigned, f);
    unsigned r = (u + 0x7FFFu + ((u >> 16) & 1u)) >> 16;
    return (unsigned short)r;
}
__device__ inline float b2f(unsigned short h) {
    unsigned u = ((unsigned)h) << 16;
    return __builtin_bit_cast(float, u);
}

// ---------------- sort + degree ----------------

__global__ void k_count(const int* __restrict__ etype, const int* __restrict__ dst,
                        int E, int N, int R, int* __restrict__ deg, int* __restrict__ counts) {
    __shared__ int lh[RMAX];
    if (threadIdx.x < RMAX) lh[threadIdx.x] = 0;
    __syncthreads();
    int e = blockIdx.x * blockDim.x + threadIdx.x;
    if (e < E) {
        int r = etype[e];
        atomicAdd(&deg[r * N + dst[e]], 1);
        atomicAdd(&lh[r], 1);
    }
    __syncthreads();
    if (threadIdx.x < R && lh[threadIdx.x])
        atomicAdd(&counts[threadIdx.x], lh[threadIdx.x]);
}

// padded offsets: each relation's range rounded up to 128 rows
__global__ void k_offsets(const int* __restrict__ counts, int* __restrict__ po,
                          int* __restrict__ cursors, int R) {
    if (threadIdx.x == 0 && blockIdx.x == 0) {
        int acc = 0;
        for (int r = 0; r < R; ++r) {
            po[r] = acc;
            cursors[r] = acc;
            acc += ((counts[r] + 127) / 128) * 128;
        }
        po[R] = acc;
    }
}

__global__ void k_scatter(const int* __restrict__ etype, int E, int R,
                          int* __restrict__ cursors, int* __restrict__ perm) {
    __shared__ int lh[RMAX];
    __shared__ int lbase[RMAX];
    __shared__ int lcur[RMAX];
    if (threadIdx.x < RMAX) lh[threadIdx.x] = 0;
    __syncthreads();
    int e = blockIdx.x * blockDim.x + threadIdx.x;
    int r = -1;
    if (e < E) { r = etype[e]; atomicAdd(&lh[r], 1); }
    __syncthreads();
    if (threadIdx.x < R) {
        lbase[threadIdx.x] = lh[threadIdx.x] ? atomicAdd(&cursors[threadIdx.x], lh[threadIdx.x]) : 0;
        lcur[threadIdx.x] = 0;
    }
    __syncthreads();
    if (e < E) {
        int pos = lbase[r] + atomicAdd(&lcur[r], 1);
        perm[pos] = e;
    }
}

// ---------------- conversions ----------------

__global__ void k_tobf16(const float* __restrict__ in, unsigned short* __restrict__ out, long n) {
    long i = ((long)blockIdx.x * 256 + threadIdx.x) * 4;
    if (i >= n) return;
    f32x4 v = *(const f32x4*)(in + i);
    unsigned u0 = (unsigned)f2b(v[0]) | ((unsigned)f2b(v[1]) << 16);
    unsigned u1 = (unsigned)f2b(v[2]) | ((unsigned)f2b(v[3]) << 16);
    uint2 t; t.x = u0; t.y = u1;
    *(uint2*)(out + i) = t;
}

// out[b][n][k] = bf16(in[b][k][n])   (batched transpose, k-minor output)
__global__ void k_transpose_b(const float* __restrict__ in, unsigned short* __restrict__ out,
                              int B, int K, int Ncol) {
    int idx = blockIdx.x * 256 + threadIdx.x;
    int per = K * Ncol;
    if (idx >= B * per) return;
    int b = idx / per, rem = idx - b * per;
    int n = rem / K, k = rem - n * K;
    out[idx] = f2b(in[(size_t)b * per + (size_t)k * Ncol + n]);
}

// ---------------- MFMA self GEMM: C[n] = x[n] @ W   (plain f32 store) ----------------

__global__ __launch_bounds__(256) void k_gemm_self(
    const unsigned short* __restrict__ xb,    // [N][D] bf16
    const unsigned short* __restrict__ wT,    // [D][D] bf16, k-minor
    float* __restrict__ C, int N)
{
    __shared__ unsigned char smA[32768];
    __shared__ unsigned char smB[32768];
    int tid = threadIdx.x;
    long row0 = (long)blockIdx.x * 128;

    {   // stage B (swizzled)
        const int4* src = (const int4*)wT;
        #pragma unroll
        for (int i = 0; i < 8; ++i) {
            int q = tid + i * 256;
            int n = q >> 4, c = q & 15;
            int4 v = src[q];
            *(int4*)(smB + n * 256 + ((c * 16) ^ ((n & 7) << 4))) = v;
        }
    }
    {   // stage A (swizzled), 2 threads per row
        int m = tid >> 1, half = tid & 1;
        long rr = row0 + m;
        int4 z = {0, 0, 0, 0};
        const int4* src = (rr < N) ? (const int4*)(xb + rr * D) : nullptr;
        for (int c = half * 8; c < half * 8 + 8; ++c) {
            int4 v = src ? src[c] : z;
            *(int4*)(smA + m * 256 + ((c * 16) ^ ((m & 7) << 4))) = v;
        }
    }
    __syncthreads();

    int lane = tid & 63, wid = tid >> 6;
    int lo = lane & 15, hi = lane >> 4;
    f32x4 acc[2][8];
    #pragma unroll
    for (int a = 0; a < 2; ++a)
        #pragma unroll
        for (int b = 0; b < 8; ++b) acc[a][b] = (f32x4){0, 0, 0, 0};

    #pragma unroll
    for (int ks = 0; ks < 4; ++ks) {
        int kb = ks * 64 + hi * 16;
        int r0 = wid * 32 + lo, r1 = r0 + 16;
        s16x8 a0 = *(const s16x8*)(smA + r0 * 256 + (kb ^ ((r0 & 7) << 4)));
        s16x8 a1 = *(const s16x8*)(smA + r1 * 256 + (kb ^ ((r1 & 7) << 4)));
        #pragma unroll
        for (int n = 0; n < 8; ++n) {
            int cr = n * 16 + lo;
            s16x8 bf = *(const s16x8*)(smB + cr * 256 + (kb ^ ((cr & 7) << 4)));
            acc[0][n] = __builtin_amdgcn_mfma_f32_16x16x32_bf16(a0, bf, acc[0][n], 0, 0, 0);
            acc[1][n] = __builtin_amdgcn_mfma_f32_16x16x32_bf16(a1, bf, acc[1][n], 0, 0, 0);
        }
    }

    #pragma unroll
    for (int m2 = 0; m2 < 2; ++m2)
        #pragma unroll
        for (int reg = 0; reg < 4; ++reg) {
            long row = row0 + wid * 32 + m2 * 16 + hi * 4 + reg;
            if (row < N) {
                #pragma unroll
                for (int n = 0; n < 8; ++n)
                    C[row * D + n * 16 + lo] = acc[m2][n][reg];
            }
        }
}

// ---------------- MFMA edge GEMM: C[dst] += (x[src] @ rw[r]) / deg ----------------

__global__ __launch_bounds__(256) void k_gemm_edge(
    const unsigned short* __restrict__ xb,    // [N][D] bf16
    const unsigned short* __restrict__ rwT,   // [R][D][D] bf16, k-minor
    const int* __restrict__ perm,             // padded, -1 = dummy
    const int* __restrict__ srcA, const int* __restrict__ dstA,
    const int* __restrict__ deg,              // [R*N]
    const int* __restrict__ po,               // [R+1]
    int N, int R, float* __restrict__ C)
{
    __shared__ unsigned char smA[32768];
    __shared__ unsigned char smB[32768];
    __shared__ float sscale[128];
    __shared__ int   sdst[128];
    int tid = threadIdx.x;
    int row0 = blockIdx.x * 128;
    if (row0 >= po[R]) return;
    int r = 0;
    while (row0 >= po[r + 1]) ++r;

    {   // stage B = rwT[r]
        const int4* src = (const int4*)(rwT + (size_t)r * D * D);
        #pragma unroll
        for (int i = 0; i < 8; ++i) {
            int q = tid + i * 256;
            int n = q >> 4, c = q & 15;
            int4 v = src[q];
            *(int4*)(smB + n * 256 + ((c * 16) ^ ((n & 7) << 4))) = v;
        }
    }
    {   // stage A = x[src[perm[row]]]
        int m = tid >> 1, half = tid & 1;
        int p = perm[row0 + m];
        const int4* src = nullptr;
        if (p >= 0) {
            if (half == 0) {
                int dv = dstA[p];
                sdst[m] = dv;
                sscale[m] = 1.0f / (float)deg[r * N + dv];
            }
            src = (const int4*)(xb + (size_t)srcA[p] * D);
        } else if (half == 0) {
            sdst[m] = -1; sscale[m] = 0.0f;
        }
        int4 z = {0, 0, 0, 0};
        for (int c = half * 8; c < half * 8 + 8; ++c) {
            int4 v = src ? src[c] : z;
            *(int4*)(smA + m * 256 + ((c * 16) ^ ((m & 7) << 4))) = v;
        }
    }
    __syncthreads();

    int lane = tid & 63, wid = tid >> 6;
    int lo = lane & 15, hi = lane >> 4;
    f32x4 acc[2][8];
    #pragma unroll
    for (int a = 0; a < 2; ++a)
        #pragma unroll
        for (int b = 0; b < 8; ++b) acc[a][b] = (f32x4){0, 0, 0, 0};

    #pragma unroll
    for (int ks = 0; ks < 4; ++ks) {
        int kb = ks * 64 + hi * 16;
        int r0 = wid * 32 + lo, r1 = r0 + 16;
        s16x8 a0 = *(const s16x8*)(smA + r0 * 256 + (kb ^ ((r0 & 7) << 4)));
        s16x8 a1 = *(const s16x8*)(smA + r1 * 256 + (kb ^ ((r1 & 7) << 4)));
        #pragma unroll
        for (int n = 0; n < 8; ++n) {
            int cr = n * 16 + lo;
            s16x8 bf = *(const s16x8*)(smB + cr * 256 + (kb ^ ((cr & 7) << 4)));
            acc[0][n] = __builtin_amdgcn_mfma_f32_16x16x32_bf16(a0, bf, acc[0][n], 0, 0, 0);
            acc[1][n] = __builtin_amdgcn_mfma_f32_16x16x32_bf16(a1, bf, acc[1][n], 0, 0, 0);
        }
    }

    #pragma unroll
    for (int m2 = 0; m2 < 2; ++m2)
        #pragma unroll
        for (int reg = 0; reg < 4; ++reg) {
            int rl = wid * 32 + m2 * 16 + hi * 4 + reg;
            int dv = sdst[rl];
            float s = sscale[rl];
            if (dv >= 0) {
                #pragma unroll
                for (int n = 0; n < 8; ++n)
                    atomicAdd(&C[(size_t)dv * D + n * 16 + lo], acc[m2][n][reg] * s);
            }
        }
}

// ---------------- finish: x = bf16( [relu](C + bias) ) ----------------

template<bool RELU>
__global__ void k_finish(const float* __restrict__ C, const float* __restrict__ bias,
                         unsigned short* __restrict__ out, long total) {
    long i = ((long)blockIdx.x * 256 + threadIdx.x) * 4;
    if (i >= total) return;
    f32x4 v = *(const f32x4*)(C + i);
    int col = (int)(i & (D - 1));
    v[0] += bias[col]; v[1] += bias[col + 1]; v[2] += bias[col + 2]; v[3] += bias[col + 3];
    if (RELU) {
        v[0] = fmaxf(v[0], 0.0f); v[1] = fmaxf(v[1], 0.0f);
        v[2] = fmaxf(v[2], 0.0f); v[3] = fmaxf(v[3], 0.0f);
    }
    unsigned u0 = (unsigned)f2b(v[0]) | ((unsigned)f2b(v[1]) << 16);
    unsigned u1 = (unsigned)f2b(v[2]) | ((unsigned)f2b(v[3]) << 16);
    uint2 t; t.x = u0; t.y = u1;
    *(uint2*)(out + i) = t;
}

// ---------------- pair scoring (MFMA over K=384 in 3 chunks) ----------------

__global__ __launch_bounds__(256) void k_score(
    const unsigned short* __restrict__ x2b,   // [N][D] bf16
    const int* __restrict__ drug, const int* __restrict__ dis,
    const unsigned short* __restrict__ pw1T,  // [128][384] bf16, k-minor
    const float* __restrict__ pb1, const float* __restrict__ pw2,
    const float* __restrict__ pb2, float* __restrict__ outp, int P)
{
    __shared__ unsigned char smA[32768];
    __shared__ unsigned char smB[32768];
    __shared__ float pb1s[128];
    __shared__ float pw2s[128];
    int tid = threadIdx.x;
    long p0 = (long)blockIdx.x * 128;
    if (tid < 128) { pb1s[tid] = pb1[tid]; pw2s[tid] = pw2[tid]; }
    float pb2v = pb2[0];

    int lane = tid & 63, wid = tid >> 6;
    int lo = lane & 15, hi = lane >> 4;
    f32x4 acc[2][8];
    #pragma unroll
    for (int a = 0; a < 2; ++a)
        #pragma unroll
        for (int b = 0; b < 8; ++b) acc[a][b] = (f32x4){0, 0, 0, 0};

    for (int ch = 0; ch < 3; ++ch) {
        {   // stage B chunk: pw1T[n][ch*128 .. +128]
            const unsigned char* pbT = (const unsigned char*)pw1T;
            #pragma unroll
            for (int i = 0; i < 8; ++i) {
                int q = tid + i * 256;
                int n = q >> 4, c = q & 15;
                int4 v = *(const int4*)(pbT + (size_t)n * 768 + ch * 256 + c * 16);
                *(int4*)(smB + n * 256 + ((c * 16) ^ ((n & 7) << 4))) = v;
            }
        }
        {   // stage A chunk
            int m = tid >> 1, half = tid & 1;
            long p = p0 + m;
            int4 z = {0, 0, 0, 0};
            if (p < P) {
                const int4* da = (const int4*)(x2b + (size_t)drug[p] * D);
                const int4* db = (const int4*)(x2b + (size_t)dis[p] * D);
                for (int c = half * 8; c < half * 8 + 8; ++c) {
                    int4 v;
                    if (ch == 0) v = da[c];
                    else if (ch == 1) v = db[c];
                    else {
                        int4 va = da[c], vb = db[c];
                        const unsigned short* ap = (const unsigned short*)&va;
                        const unsigned short* bp = (const unsigned short*)&vb;
                        unsigned short o[8];
                        #pragma unroll
                        for (int j = 0; j < 8; ++j) o[j] = f2b(b2f(ap[j]) * b2f(bp[j]));
                        v = *(const int4*)o;
                    }
                    *(int4*)(smA + m * 256 + ((c * 16) ^ ((m & 7) << 4))) = v;
                }
            } else {
                for (int c = half * 8; c < half * 8 + 8; ++c)
                    *(int4*)(smA + m * 256 + ((c * 16) ^ ((m & 7) << 4))) = z;
            }
        }
        __syncthreads();

        #pragma unroll
        for (int ks = 0; ks < 4; ++ks) {
            int kb = ks * 64 + hi * 16;
            int r0 = wid * 32 + lo, r1 = r0 + 16;
            s16x8 a0 = *(const s16x8*)(smA + r0 * 256 + (kb ^ ((r0 & 7) << 4)));
            s16x8 a1 = *(const s16x8*)(smA + r1 * 256 + (kb ^ ((r1 & 7) << 4)));
            #pragma unroll
            for (int n = 0; n < 8; ++n) {
                int cr = n * 16 + lo;
                s16x8 bf = *(const s16x8*)(smB + cr * 256 + (kb ^ ((cr & 7) << 4)));
                acc[0][n] = __builtin_amdgcn_mfma_f32_16x16x32_bf16(a0, bf, acc[0][n], 0, 0, 0);
                acc[1][n] = __builtin_amdgcn_mfma_f32_16x16x32_bf16(a1, bf, acc[1][n], 0, 0, 0);
            }
        }
        __syncthreads();
    }

    // epilogue: logit = sum_col relu(acc + pb1) * pw2 + pb2
    #pragma unroll
    for (int m2 = 0; m2 < 2; ++m2)
        #pragma unroll
        for (int reg = 0; reg < 4; ++reg) {
            float s = 0.0f;
            #pragma unroll
            for (int n = 0; n < 8; ++n) {
                int col = n * 16 + lo;
                float v = acc[m2][n][reg] + pb1s[col];
                v = fmaxf(v, 0.0f);
                s = fmaf(v, pw2s[col], s);
            }
            s += __shfl_xor(s, 1, 64);
            s += __shfl_xor(s, 2, 64);
            s += __shfl_xor(s, 4, 64);
            s += __shfl_xor(s, 8, 64);
            long p = p0 + wid * 32 + m2 * 16 + hi * 4 + reg;
            if (lo == 0 && p < P) outp[p] = s + pb2v;
        }
}

// ---------------- launch ----------------

extern "C" void kernel_launch(void* const* d_in, const int* in_sizes, int n_in,
                              void* d_out, int out_size, void* d_ws, size_t ws_size,
                              hipStream_t stream) {
    const int*   edge_index = (const int*)d_in[0];
    const int*   edge_type  = (const int*)d_in[1];
    const int*   drug       = (const int*)d_in[2];
    const int*   dis        = (const int*)d_in[3];
    const float* emb        = (const float*)d_in[4];
    const float* rw1        = (const float*)d_in[5];
    const float* sl1        = (const float*)d_in[6];
    const float* b1         = (const float*)d_in[7];
    const float* rw2        = (const float*)d_in[8];
    const float* sl2        = (const float*)d_in[9];
    const float* b2         = (const float*)d_in[10];
    const float* pw1        = (const float*)d_in[11];
    const float* pb1        = (const float*)d_in[12];
    const float* pw2        = (const float*)d_in[13];
    const float* pb2        = (const float*)d_in[14];

    const int E = in_sizes[1];
    const int P = in_sizes[2];
    const int N = in_sizes[4] / D;
    const int R = in_sizes[5] / (D * D);

    const int* srcA = edge_index;
    const int* dstA = edge_index + E;

    char* ws = (char*)d_ws;
    unsigned short* embb = (unsigned short*)ws; ws += (size_t)N * D * 2;  // aliased as x2b later
    unsigned short* x1b  = (unsigned short*)ws; ws += (size_t)N * D * 2;
    float* C             = (float*)ws;          ws += (size_t)N * D * 4;
    unsigned short* rw1T = (unsigned short*)ws; ws += (size_t)R * D * D * 2;
    unsigned short* rw2T = (unsigned short*)ws; ws += (size_t)R * D * D * 2;
    unsigned short* sl1T = (unsigned short*)ws; ws += (size_t)D * D * 2;
    unsigned short* sl2T = (unsigned short*)ws; ws += (size_t)D * D * 2;
    unsigned short* pw1T = (unsigned short*)ws; ws += (size_t)3 * D * D * 2;
    int* deg   = (int*)ws; ws += (size_t)R * N * 4;
    int* perm  = (int*)ws; ws += (size_t)(E + R * 128) * 4;
    int* counts = (int*)ws; ws += 256;
    int* po     = (int*)ws; ws += 256;
    int* cursors = (int*)ws; ws += 256;
    unsigned short* x2b = embb;   // reuse: emb no longer needed when x2 is produced

    hipMemsetAsync(deg, 0, (size_t)R * N * 4, stream);
    hipMemsetAsync(counts, 0, 256, stream);
    hipMemsetAsync(perm, 0xFF, (size_t)(E + R * 128) * 4, stream);

    k_count  <<<(E + 255) / 256, 256, 0, stream>>>(edge_type, dstA, E, N, R, deg, counts);
    k_offsets<<<1, 1, 0, stream>>>(counts, po, cursors, R);
    k_scatter<<<(E + 255) / 256, 256, 0, stream>>>(edge_type, E, R, cursors, perm);

    long nd = (long)N * D;
    k_tobf16<<<(int)((nd / 4 + 255) / 256), 256, 0, stream>>>(emb, embb, nd);
    k_transpose_b<<<(R * D * D + 255) / 256, 256, 0, stream>>>(rw1, rw1T, R, D, D);
    k_transpose_b<<<(R * D * D + 255) / 256, 256, 0, stream>>>(rw2, rw2T, R, D, D);
    k_transpose_b<<<(D * D + 255) / 256, 256, 0, stream>>>(sl1, sl1T, 1, D, D);
    k_transpose_b<<<(D * D + 255) / 256, 256, 0, stream>>>(sl2, sl2T, 1, D, D);
    k_transpose_b<<<(3 * D * D + 255) / 256, 256, 0, stream>>>(pw1, pw1T, 1, 3 * D, D);

    int gridN = (N + 127) / 128;
    int gridE = (E + 127) / 128 + R;

    // layer 1
    k_gemm_self<<<gridN, 256, 0, stream>>>(embb, sl1T, C, N);
    k_gemm_edge<<<gridE, 256, 0, stream>>>(embb, rw1T, perm, srcA, dstA, deg, po, N, R, C);
    k_finish<true><<<(int)((nd / 4 + 255) / 256), 256, 0, stream>>>(C, b1, x1b, nd);
    // layer 2
    k_gemm_self<<<gridN, 256, 0, stream>>>(x1b, sl2T, C, N);
    k_gemm_edge<<<gridE, 256, 0, stream>>>(x1b, rw2T, perm, srcA, dstA, deg, po, N, R, C);
    k_finish<false><<<(int)((nd / 4 + 255) / 256), 256, 0, stream>>>(C, b2, x2b, nd);
    // scoring
    k_score<<<(P + 127) / 128, 256, 0, stream>>>(x2b, drug, dis, pw1T, pb1, pw2, pb2,
                                                 (float*)d_out, P);
}

// Round 4
// 513.785 us; speedup vs baseline: 11.4294x; 1.4260x over previous
//
#include <hip/hip_runtime.h>

#define D 128
#define RMAX 16

typedef short s16x8 __attribute__((ext_vector_type(8)));
typedef float f32x4 __attribute__((ext_vector_type(4)));

__device__ inline unsigned short f2b(float f) {
    unsigned u = __builtin_bit_cast(unsigned, f);
    unsigned r = (u + 0x7FFFu + ((u >> 16) & 1u)) >> 16;
    return (unsigned short)r;
}
__device__ inline float b2f(unsigned short h) {
    unsigned u = ((unsigned)h) << 16;
    return __builtin_bit_cast(float, u);
}

// ---------------- sort + degree ----------------

__global__ void k_count(const int* __restrict__ etype, const int* __restrict__ dst,
                        int E, int N, int R, int* __restrict__ deg, int* __restrict__ counts) {
    __shared__ int lh[RMAX];
    if (threadIdx.x < RMAX) lh[threadIdx.x] = 0;
    __syncthreads();
    int e = blockIdx.x * blockDim.x + threadIdx.x;
    if (e < E) {
        int r = etype[e];
        atomicAdd(&deg[r * N + dst[e]], 1);
        atomicAdd(&lh[r], 1);
    }
    __syncthreads();
    if (threadIdx.x < R && lh[threadIdx.x])
        atomicAdd(&counts[threadIdx.x], lh[threadIdx.x]);
}

// padded offsets, plus a final "self" pseudo-relation of N rows
__global__ void k_offsets(const int* __restrict__ counts, int* __restrict__ po,
                          int* __restrict__ cursors, int R, int N) {
    if (threadIdx.x == 0 && blockIdx.x == 0) {
        int acc = 0;
        for (int r = 0; r < R; ++r) {
            po[r] = acc;
            cursors[r] = acc;
            acc += ((counts[r] + 127) / 128) * 128;
        }
        po[R] = acc;
        acc += ((N + 127) / 128) * 128;
        po[R + 1] = acc;
    }
}

__global__ void k_scatter(const int* __restrict__ etype, int E, int R,
                          int* __restrict__ cursors, int* __restrict__ perm) {
    __shared__ int lh[RMAX];
    __shared__ int lbase[RMAX];
    __shared__ int lcur[RMAX];
    if (threadIdx.x < RMAX) lh[threadIdx.x] = 0;
    __syncthreads();
    int e = blockIdx.x * blockDim.x + threadIdx.x;
    int r = -1;
    if (e < E) { r = etype[e]; atomicAdd(&lh[r], 1); }
    __syncthreads();
    if (threadIdx.x < R) {
        lbase[threadIdx.x] = lh[threadIdx.x] ? atomicAdd(&cursors[threadIdx.x], lh[threadIdx.x]) : 0;
        lcur[threadIdx.x] = 0;
    }
    __syncthreads();
    if (e < E) {
        int pos = lbase[r] + atomicAdd(&lcur[r], 1);
        perm[pos] = e;
    }
}

// self pseudo-edges occupy perm[po[R] + n] = E + n
__global__ void k_selfperm(const int* __restrict__ po, int R, int E, int N,
                           int* __restrict__ perm) {
    int n = blockIdx.x * 256 + threadIdx.x;
    if (n < N) perm[po[R] + n] = E + n;
}

// ---------------- dst-segment offsets (indeg+1, prefix scan) ----------------

__global__ void k_indeg(const int* __restrict__ deg, int* __restrict__ cnt, int N, int R) {
    int d = blockIdx.x * 256 + threadIdx.x;
    if (d < N) {
        int s = 1;   // self slot
        for (int r = 0; r < R; ++r) s += deg[r * N + d];
        cnt[d] = s;
    }
}

__global__ void k_scan1(const int* __restrict__ cnt, int* __restrict__ tmp,
                        int* __restrict__ bsum, int N) {
    __shared__ int sd[256];
    int t = threadIdx.x;
    int base = blockIdx.x * 1024 + t * 4;
    int s[4];
    #pragma unroll
    for (int k = 0; k < 4; ++k) s[k] = (base + k < N) ? cnt[base + k] : 0;
    int tsum = s[0] + s[1] + s[2] + s[3];
    sd[t] = tsum;
    __syncthreads();
    for (int off = 1; off < 256; off <<= 1) {
        int v = (t >= off) ? sd[t - off] : 0;
        __syncthreads();
        sd[t] += v;
        __syncthreads();
    }
    int excl = sd[t] - tsum;
    int run = excl;
    #pragma unroll
    for (int k = 0; k < 4; ++k) {
        if (base + k < N) tmp[base + k] = run;
        run += s[k];
    }
    if (t == 255) bsum[blockIdx.x] = sd[255];
}

__global__ void k_scan2(const int* __restrict__ bsum, int* __restrict__ boff,
                        int nb, int* __restrict__ rowstart, int N, int total) {
    __shared__ int sd[256];
    int t = threadIdx.x;
    int v = (t < nb) ? bsum[t] : 0;
    sd[t] = v;
    __syncthreads();
    for (int off = 1; off < 256; off <<= 1) {
        int w = (t >= off) ? sd[t - off] : 0;
        __syncthreads();
        sd[t] += w;
        __syncthreads();
    }
    if (t < nb) boff[t] = sd[t] - v;
    if (t == 0) rowstart[N] = total;
}

__global__ void k_scan3(const int* __restrict__ tmp, const int* __restrict__ boff,
                        int* __restrict__ rowstart, int N) {
    int i = blockIdx.x * 256 + threadIdx.x;
    if (i < N) rowstart[i] = tmp[i] + boff[i >> 10];
}

// per-edge dst-sorted slot; self slot first in each segment
__global__ void k_dstpos(const int* __restrict__ dstA, const int* __restrict__ rowstart,
                         int* __restrict__ cur2, int* __restrict__ dstpos, int E, int N) {
    int t = blockIdx.x * 256 + threadIdx.x;
    if (t < E) {
        int d = dstA[t];
        int rank = atomicAdd(&cur2[d], 1);
        dstpos[t] = rowstart[d] + 1 + rank;
    } else if (t < E + N) {
        dstpos[t] = rowstart[t - E];
    }
}

// ---------------- conversions ----------------

__global__ void k_tobf16(const float* __restrict__ in, unsigned short* __restrict__ out, long n) {
    long i = ((long)blockIdx.x * 256 + threadIdx.x) * 4;
    if (i >= n) return;
    f32x4 v = *(const f32x4*)(in + i);
    unsigned u0 = (unsigned)f2b(v[0]) | ((unsigned)f2b(v[1]) << 16);
    unsigned u1 = (unsigned)f2b(v[2]) | ((unsigned)f2b(v[3]) << 16);
    uint2 t; t.x = u0; t.y = u1;
    *(uint2*)(out + i) = t;
}

// out[b][n][k] = bf16(in[b][k][n])
__global__ void k_transpose_b(const float* __restrict__ in, unsigned short* __restrict__ out,
                              int B, int K, int Ncol) {
    int idx = blockIdx.x * 256 + threadIdx.x;
    int per = K * Ncol;
    if (idx >= B * per) return;
    int b = idx / per, rem = idx - b * per;
    int n = rem / K, k = rem - n * K;
    out[idx] = f2b(in[(size_t)b * per + (size_t)k * Ncol + n]);
}

// ---------------- phase A: per-edge scaled messages via MFMA ----------------
// y[dstpos[e]] = bf16( (x[src_e] @ W_{r_e}) * scale_e ),  self rows: W=sl, scale=1

__global__ __launch_bounds__(256) void k_gemm_msg(
    const unsigned short* __restrict__ xb,    // [N][D] bf16
    const unsigned short* __restrict__ wAll,  // [(R+1)][D][D] bf16, k-minor
    const int* __restrict__ perm,
    const int* __restrict__ srcA, const int* __restrict__ dstA,
    const int* __restrict__ deg, const int* __restrict__ dstpos,
    const int* __restrict__ po, int E, int N, int Rt,
    unsigned short* __restrict__ y)
{
    __shared__ unsigned char smB[32768];
    __shared__ int   ssrc[128];
    __shared__ float sscale[128];
    __shared__ int   sdp[128];
    int tid = threadIdx.x;
    int row0 = blockIdx.x * 128;
    if (row0 >= po[Rt]) return;
    int r = 0;
    while (row0 >= po[r + 1]) ++r;

    if (tid < 128) {
        int p = perm[row0 + tid];
        int sv = 0; float sc = 0.0f; int dp = -1;
        if (p >= 0) {
            dp = dstpos[p];
            if (p < E) { sv = srcA[p]; sc = 1.0f / (float)deg[r * N + dstA[p]]; }
            else       { sv = p - E;   sc = 1.0f; }
        }
        ssrc[tid] = sv; sscale[tid] = sc; sdp[tid] = dp;
    }
    {   // stage B = wAll[r], swizzled
        const int4* src = (const int4*)(wAll + (size_t)r * D * D);
        #pragma unroll
        for (int i = 0; i < 8; ++i) {
            int q = tid + i * 256;
            int n = q >> 4, c = q & 15;
            int4 v = src[q];
            *(int4*)(smB + n * 256 + ((c * 16) ^ ((n & 7) << 4))) = v;
        }
    }
    __syncthreads();

    int lane = tid & 63, wid = tid >> 6;
    int lo = lane & 15, hi = lane >> 4;
    int r0g = wid * 32 + lo, r1g = r0g + 16;
    const unsigned short* xrow0 = xb + (size_t)ssrc[r0g] * D;
    const unsigned short* xrow1 = xb + (size_t)ssrc[r1g] * D;

    f32x4 acc[2][8];
    #pragma unroll
    for (int a = 0; a < 2; ++a)
        #pragma unroll
        for (int b = 0; b < 8; ++b) acc[a][b] = (f32x4){0, 0, 0, 0};

    #pragma unroll
    for (int ks = 0; ks < 4; ++ks) {
        s16x8 a0 = *(const s16x8*)(xrow0 + ks * 32 + hi * 8);   // A direct from global
        s16x8 a1 = *(const s16x8*)(xrow1 + ks * 32 + hi * 8);
        int kb = ks * 64 + hi * 16;
        #pragma unroll
        for (int n = 0; n < 8; ++n) {
            int cr = n * 16 + lo;
            s16x8 bf = *(const s16x8*)(smB + cr * 256 + (kb ^ ((cr & 7) << 4)));
            acc[0][n] = __builtin_amdgcn_mfma_f32_16x16x32_bf16(a0, bf, acc[0][n], 0, 0, 0);
            acc[1][n] = __builtin_amdgcn_mfma_f32_16x16x32_bf16(a1, bf, acc[1][n], 0, 0, 0);
        }
    }

    __syncthreads();   // B reads done; reuse smB as bf16 store-staging [128 rows][256 B]
    #pragma unroll
    for (int m2 = 0; m2 < 2; ++m2) {
        int rbase = wid * 32 + m2 * 16 + hi * 4;
        #pragma unroll
        for (int reg = 0; reg < 4; ++reg) {
            int rl = rbase + reg;
            float s = sscale[rl];
            #pragma unroll
            for (int n = 0; n < 8; ++n) {
                int byteoff = rl * 256 + (((n * 32 + (lo >> 3) * 16) ^ ((rl & 7) << 4)) + (lo & 7) * 2);
                *(unsigned short*)(smB + byteoff) = f2b(acc[m2][n][reg] * s);
            }
        }
    }
    __syncthreads();
    {
        int m = tid >> 1, half = tid & 1;
        int dp = sdp[m];
        if (dp >= 0) {
            unsigned short* dst = y + (size_t)dp * D;
            #pragma unroll
            for (int i = 0; i < 8; ++i) {
                int c = half * 8 + i;
                int4 v = *(const int4*)(smB + m * 256 + ((c * 16) ^ ((m & 7) << 4)));
                *(int4*)(dst + c * 8) = v;
            }
        }
    }
}

// ---------------- phase B: segmented sum over dst segments ----------------

template<bool RELU>
__global__ void k_reduce(const unsigned short* __restrict__ y,
                         const int* __restrict__ rowstart,
                         const float* __restrict__ bias,
                         unsigned short* __restrict__ out, int N)
{
    int tid = threadIdx.x;
    int dl = tid >> 6, cj = tid & 63;
    int dbase = blockIdx.x * 16 + dl * 4;
    float b0 = bias[cj * 2], b1 = bias[cj * 2 + 1];
    for (int i = 0; i < 4; ++i) {
        int d = dbase + i;
        if (d >= N) return;
        int s = rowstart[d], e = rowstart[d + 1];
        float a0 = b0, a1 = b1;
        for (int pos = s; pos < e; ++pos) {
            unsigned v = *(const unsigned*)(y + (size_t)pos * D + cj * 2);
            a0 += __builtin_bit_cast(float, (v & 0xFFFFu) << 16);
            a1 += __builtin_bit_cast(float, v & 0xFFFF0000u);
        }
        if (RELU) { a0 = fmaxf(a0, 0.0f); a1 = fmaxf(a1, 0.0f); }
        unsigned o = (unsigned)f2b(a0) | ((unsigned)f2b(a1) << 16);
        *(unsigned*)(out + (size_t)d * D + cj * 2) = o;
    }
}

// ---------------- pair scoring (MFMA over K=384 in 3 chunks) ----------------

__global__ __launch_bounds__(256) void k_score(
    const unsigned short* __restrict__ x2b,
    const int* __restrict__ drug, const int* __restrict__ dis,
    const unsigned short* __restrict__ pw1T,  // [128][384] bf16, k-minor
    const float* __restrict__ pb1, const float* __restrict__ pw2,
    const float* __restrict__ pb2, float* __restrict__ outp, int P)
{
    __shared__ unsigned char smA[32768];
    __shared__ unsigned char smB[32768];
    __shared__ float pb1s[128];
    __shared__ float pw2s[128];
    int tid = threadIdx.x;
    long p0 = (long)blockIdx.x * 128;
    if (tid < 128) { pb1s[tid] = pb1[tid]; pw2s[tid] = pw2[tid]; }
    float pb2v = pb2[0];

    int lane = tid & 63, wid = tid >> 6;
    int lo = lane & 15, hi = lane >> 4;
    f32x4 acc[2][8];
    #pragma unroll
    for (int a = 0; a < 2; ++a)
        #pragma unroll
        for (int b = 0; b < 8; ++b) acc[a][b] = (f32x4){0, 0, 0, 0};

    for (int ch = 0; ch < 3; ++ch) {
        {
            const unsigned char* pbT = (const unsigned char*)pw1T;
            #pragma unroll
            for (int i = 0; i < 8; ++i) {
                int q = tid + i * 256;
                int n = q >> 4, c = q & 15;
                int4 v = *(const int4*)(pbT + (size_t)n * 768 + ch * 256 + c * 16);
                *(int4*)(smB + n * 256 + ((c * 16) ^ ((n & 7) << 4))) = v;
            }
        }
        {
            int m = tid >> 1, half = tid & 1;
            long p = p0 + m;
            int4 z = {0, 0, 0, 0};
            if (p < P) {
                const int4* da = (const int4*)(x2b + (size_t)drug[p] * D);
                const int4* db = (const int4*)(x2b + (size_t)dis[p] * D);
                for (int c = half * 8; c < half * 8 + 8; ++c) {
                    int4 v;
                    if (ch == 0) v = da[c];
                    else if (ch == 1) v = db[c];
                    else {
                        int4 va = da[c], vb = db[c];
                        const unsigned short* ap = (const unsigned short*)&va;
                        const unsigned short* bp = (const unsigned short*)&vb;
                        unsigned short o[8];
                        #pragma unroll
                        for (int j = 0; j < 8; ++j) o[j] = f2b(b2f(ap[j]) * b2f(bp[j]));
                        v = *(const int4*)o;
                    }
                    *(int4*)(smA + m * 256 + ((c * 16) ^ ((m & 7) << 4))) = v;
                }
            } else {
                for (int c = half * 8; c < half * 8 + 8; ++c)
                    *(int4*)(smA + m * 256 + ((c * 16) ^ ((m & 7) << 4))) = z;
            }
        }
        __syncthreads();

        #pragma unroll
        for (int ks = 0; ks < 4; ++ks) {
            int kb = ks * 64 + hi * 16;
            int r0 = wid * 32 + lo, r1 = r0 + 16;
            s16x8 a0 = *(const s16x8*)(smA + r0 * 256 + (kb ^ ((r0 & 7) << 4)));
            s16x8 a1 = *(const s16x8*)(smA + r1 * 256 + (kb ^ ((r1 & 7) << 4)));
            #pragma unroll
            for (int n = 0; n < 8; ++n) {
                int cr = n * 16 + lo;
                s16x8 bf = *(const s16x8*)(smB + cr * 256 + (kb ^ ((cr & 7) << 4)));
                acc[0][n] = __builtin_amdgcn_mfma_f32_16x16x32_bf16(a0, bf, acc[0][n], 0, 0, 0);
                acc[1][n] = __builtin_amdgcn_mfma_f32_16x16x32_bf16(a1, bf, acc[1][n], 0, 0, 0);
            }
        }
        __syncthreads();
    }

    #pragma unroll
    for (int m2 = 0; m2 < 2; ++m2)
        #pragma unroll
        for (int reg = 0; reg < 4; ++reg) {
            float s = 0.0f;
            #pragma unroll
            for (int n = 0; n < 8; ++n) {
                int col = n * 16 + lo;
                float v = acc[m2][n][reg] + pb1s[col];
                v = fmaxf(v, 0.0f);
                s = fmaf(v, pw2s[col], s);
            }
            s += __shfl_xor(s, 1, 64);
            s += __shfl_xor(s, 2, 64);
            s += __shfl_xor(s, 4, 64);
            s += __shfl_xor(s, 8, 64);
            long p = p0 + wid * 32 + m2 * 16 + hi * 4 + reg;
            if (lo == 0 && p < P) outp[p] = s + pb2v;
        }
}

// ---------------- launch ----------------

extern "C" void kernel_launch(void* const* d_in, const int* in_sizes, int n_in,
                              void* d_out, int out_size, void* d_ws, size_t ws_size,
                              hipStream_t stream) {
    const int*   edge_index = (const int*)d_in[0];
    const int*   edge_type  = (const int*)d_in[1];
    const int*   drug       = (const int*)d_in[2];
    const int*   dis        = (const int*)d_in[3];
    const float* emb        = (const float*)d_in[4];
    const float* rw1        = (const float*)d_in[5];
    const float* sl1        = (const float*)d_in[6];
    const float* b1         = (const float*)d_in[7];
    const float* rw2        = (const float*)d_in[8];
    const float* sl2        = (const float*)d_in[9];
    const float* b2         = (const float*)d_in[10];
    const float* pw1        = (const float*)d_in[11];
    const float* pb1        = (const float*)d_in[12];
    const float* pw2        = (const float*)d_in[13];
    const float* pb2        = (const float*)d_in[14];

    const int E = in_sizes[1];
    const int P = in_sizes[2];
    const int N = in_sizes[4] / D;
    const int R = in_sizes[5] / (D * D);

    const int* srcA = edge_index;
    const int* dstA = edge_index + E;

    const int permN = E + ((N + 127) / 128) * 128 + (R + 1) * 128;

    char* ws = (char*)d_ws;
    unsigned short* embb = (unsigned short*)ws; ws += (size_t)N * D * 2;   // aliased as x2b
    unsigned short* x1b  = (unsigned short*)ws; ws += (size_t)N * D * 2;
    unsigned short* y    = (unsigned short*)ws; ws += (size_t)(E + N) * D * 2;
    unsigned short* wAll1 = (unsigned short*)ws; ws += (size_t)(R + 1) * D * D * 2;
    unsigned short* wAll2 = (unsigned short*)ws; ws += (size_t)(R + 1) * D * D * 2;
    unsigned short* pw1T  = (unsigned short*)ws; ws += (size_t)3 * D * D * 2;
    int* deg     = (int*)ws; ws += (size_t)R * N * 4;
    int* perm    = (int*)ws; ws += (size_t)permN * 4;
    int* dstpos  = (int*)ws; ws += (size_t)(E + N) * 4;
    int* cnt     = (int*)ws; ws += (size_t)N * 4;
    int* tmp     = (int*)ws; ws += (size_t)N * 4;
    int* rowstart = (int*)ws; ws += (size_t)(N + 1) * 4;
    int* cur2    = (int*)ws; ws += (size_t)N * 4;
    int* bsum    = (int*)ws; ws += 256 * 4;
    int* boff    = (int*)ws; ws += 256 * 4;
    int* counts  = (int*)ws; ws += 256;
    int* po      = (int*)ws; ws += 256;
    int* cursors = (int*)ws; ws += 256;
    unsigned short* x2b = embb;

    hipMemsetAsync(deg, 0, (size_t)R * N * 4, stream);
    hipMemsetAsync(counts, 0, 256, stream);
    hipMemsetAsync(cur2, 0, (size_t)N * 4, stream);
    hipMemsetAsync(perm, 0xFF, (size_t)permN * 4, stream);

    k_count  <<<(E + 255) / 256, 256, 0, stream>>>(edge_type, dstA, E, N, R, deg, counts);
    k_offsets<<<1, 1, 0, stream>>>(counts, po, cursors, R, N);
    k_scatter<<<(E + 255) / 256, 256, 0, stream>>>(edge_type, E, R, cursors, perm);
    k_selfperm<<<(N + 255) / 256, 256, 0, stream>>>(po, R, E, N, perm);

    k_indeg<<<(N + 255) / 256, 256, 0, stream>>>(deg, cnt, N, R);
    int nb1 = (N + 1023) / 1024;
    k_scan1<<<nb1, 256, 0, stream>>>(cnt, tmp, bsum, N);
    k_scan2<<<1, 256, 0, stream>>>(bsum, boff, nb1, rowstart, N, E + N);
    k_scan3<<<(N + 255) / 256, 256, 0, stream>>>(tmp, boff, rowstart, N);
    k_dstpos<<<(E + N + 255) / 256, 256, 0, stream>>>(dstA, rowstart, cur2, dstpos, E, N);

    long nd = (long)N * D;
    k_tobf16<<<(int)((nd / 4 + 255) / 256), 256, 0, stream>>>(emb, embb, nd);
    k_transpose_b<<<(R * D * D + 255) / 256, 256, 0, stream>>>(rw1, wAll1, R, D, D);
    k_transpose_b<<<(D * D + 255) / 256, 256, 0, stream>>>(sl1, wAll1 + (size_t)R * D * D, 1, D, D);
    k_transpose_b<<<(R * D * D + 255) / 256, 256, 0, stream>>>(rw2, wAll2, R, D, D);
    k_transpose_b<<<(D * D + 255) / 256, 256, 0, stream>>>(sl2, wAll2 + (size_t)R * D * D, 1, D, D);
    k_transpose_b<<<(3 * D * D + 255) / 256, 256, 0, stream>>>(pw1, pw1T, 1, 3 * D, D);

    int gridM = (E + 127) / 128 + (N + 127) / 128 + R + 2;
    int gridR = (N + 15) / 16;

    // layer 1
    k_gemm_msg<<<gridM, 256, 0, stream>>>(embb, wAll1, perm, srcA, dstA, deg, dstpos,
                                          po, E, N, R + 1, y);
    k_reduce<true><<<gridR, 256, 0, stream>>>(y, rowstart, b1, x1b, N);
    // layer 2
    k_gemm_msg<<<gridM, 256, 0, stream>>>(x1b, wAll2, perm, srcA, dstA, deg, dstpos,
                                          po, E, N, R + 1, y);
    k_reduce<false><<<gridR, 256, 0, stream>>>(y, rowstart, b2, x2b, N);
    // scoring
    k_score<<<(P + 127) / 128, 256, 0, stream>>>(x2b, drug, dis, pw1T, pb1, pw2, pb2,
                                                 (float*)d_out, P);
}